// Round 6
// baseline (163.748 us; speedup 1.0000x reference)
//
#include <hip/hip_runtime.h>

#define N_NODES 10000
#define N_EDGES 320000
#define N_PAIRS 2048
#define IN_CH 128
#define HIDDEN 512
#define PPB 8
#define WIDTH 160        // max degree ~Binom(640K,1e-4): mean 64, max≈104 << 160
#define NSLOT 4096
#define NBLK 256
#define NTHR 256

// ---------------------------------------------------------------------------
// Workspace layout (int units):
//   slotmap [0, 10240)       node -> canonical tar slot, -1 if not a target
//   cnt     [10240, 14336)   per-slot fill count
//   bar     [14336, 14344)   grid-barrier counter (zeroed by k_init)
//   adjC    [14400, 342080)  ushort[NSLOT][WIDTH] compact adjacency (1.3 MB, L2-fit)
// ---------------------------------------------------------------------------

// Single block: __syncthreads gives us init -> map ordering without a grid sync.
__global__ __launch_bounds__(1024) void k_init(const int* __restrict__ tar,
                                               int* __restrict__ ws) {
    const int t = threadIdx.x;
    for (int i = t; i < 14344; i += 1024) ws[i] = (i < 10240) ? -1 : 0;
    __syncthreads();
    // last-writer-wins canonical slot (any slot holding this node works)
    for (int s = t; s < 2 * N_PAIRS; s += 1024) ws[tar[s]] = s;
}

__global__ __launch_bounds__(NTHR, 4) void k_mega(
    const float* __restrict__ x,
    const int* __restrict__ ei,
    const int* __restrict__ tar,
    const float* __restrict__ W1,
    const float* __restrict__ b1,
    const float* __restrict__ W2,
    const float* __restrict__ b2,
    float* __restrict__ out,
    int* __restrict__ ws) {
    int* slotmap = ws;
    int* cnt = ws + 10240;
    int* bar = ws + 14336;
    unsigned short* adjC = (unsigned short*)(ws + 14400);

    const int tid = threadIdx.x;
    __shared__ unsigned short adjJ[PPB][WIDTH];
    __shared__ float sxs[PPB][2 * IN_CH];
    __shared__ float red[PPB][4];

    // ---- Phase C: scatter both edge directions into target-node rows ----
    for (int e = blockIdx.x * NTHR + tid; e < N_EDGES; e += NBLK * NTHR) {
        const int s = ei[e];
        const int d = ei[N_EDGES + e];
        int sl = slotmap[s];
        if (sl >= 0) {
            const int p = atomicAdd(&cnt[sl], 1);
            if (p < WIDTH) adjC[sl * WIDTH + p] = (unsigned short)d;
        }
        sl = slotmap[d];
        if (sl >= 0) {
            const int p = atomicAdd(&cnt[sl], 1);
            if (p < WIDTH) adjC[sl * WIDTH + p] = (unsigned short)s;
        }
    }

    // ---- Grid barrier (all 256 blocks co-resident by construction) ----
    __syncthreads();
    if (tid == 0) {
        __threadfence();  // release: push adjC/cnt out of this XCD's L2
        __hip_atomic_fetch_add(&bar[0], 1, __ATOMIC_ACQ_REL, __HIP_MEMORY_SCOPE_AGENT);
        while (__hip_atomic_load(&bar[0], __ATOMIC_ACQUIRE, __HIP_MEMORY_SCOPE_AGENT) < NBLK)
            __builtin_amdgcn_s_sleep(2);
        __threadfence();  // acquire: invalidate stale lines before reads
    }
    __syncthreads();

    // ---- Phase D: pair features into LDS. Wave w handles pairs w and w+4 ----
    {
        const int wid = tid >> 6;
        const int lane = tid & 63;
        for (int pi = 0; pi < 2; ++pi) {
            const int p = wid + pi * 4;
            const int pr = blockIdx.x * PPB + p;
            const int ti = tar[pr];
            const int tj = tar[N_PAIRS + pr];
            const int si = slotmap[ti];
            const int sj = slotmap[tj];
            int cj = cnt[sj]; cj = cj < WIDTH ? cj : WIDTH;
            int ci = cnt[si]; ci = ci < WIDTH ? ci : WIDTH;
            for (int q = lane; q < cj; q += 64) adjJ[p][q] = adjC[sj * WIDTH + q];
            // wave-private LDS slice: compiler's lgkmcnt covers write->read
            float c0 = 0.0f, c1 = 0.0f;
            const int cir = (ci + 63) & ~63;
            for (int pp = lane; pp < cir; pp += 64) {
                const int u = (pp < ci) ? (int)adjC[si * WIDTH + pp] : 0x7FFFFFFF;
                int cm = 0;
                for (int q = 0; q < cj; ++q) cm += ((int)adjJ[p][q] == u) ? 1 : 0;
                unsigned long long m = __ballot(cm > 0);
                while (m) {  // ~0.4 matches/pair: wave-parallel gather of x[u]
                    const int l2 = __ffsll(m) - 1;
                    m &= m - 1;
                    const int uu = __shfl(u, l2, 64);
                    const float fc = (float)__shfl(cm, l2, 64);
                    c0 += fc * x[uu * IN_CH + lane];
                    c1 += fc * x[uu * IN_CH + 64 + lane];
                }
            }
            sxs[p][128 + lane] = c0;
            sxs[p][192 + lane] = c1;
            sxs[p][lane]      = x[ti * IN_CH + lane] * x[tj * IN_CH + lane];
            sxs[p][64 + lane] = x[ti * IN_CH + 64 + lane] * x[tj * IN_CH + 64 + lane];
        }
    }
    __syncthreads();

    // ---- Phase E: MLP. Thread j owns hidden units j and j+256; W1 L2-resident ----
    const float bja = b1[tid], bjb = b1[tid + 256];
    const float w2a = W2[tid], w2b = W2[tid + 256];
    float acc0[PPB], acc1[PPB];
#pragma unroll
    for (int p = 0; p < PPB; ++p) { acc0[p] = 0.0f; acc1[p] = 0.0f; }
#pragma unroll 8
    for (int k = 0; k < 2 * IN_CH; ++k) {
        const float wa = W1[k * HIDDEN + tid];
        const float wb = W1[k * HIDDEN + tid + 256];
#pragma unroll
        for (int p = 0; p < PPB; ++p) {
            acc0[p] = fmaf(sxs[p][k], wa, acc0[p]);
            acc1[p] = fmaf(sxs[p][k], wb, acc1[p]);
        }
    }
    const int lane = tid & 63;
    const int wid = tid >> 6;
#pragma unroll
    for (int p = 0; p < PPB; ++p) {
        float ha = acc0[p] + bja; ha = ha > 0.0f ? ha : 0.0f;
        float hb = acc1[p] + bjb; hb = hb > 0.0f ? hb : 0.0f;
        float part = ha * w2a + hb * w2b;
        for (int off = 32; off >= 1; off >>= 1)
            part += __shfl_down(part, off, 64);
        if (lane == 0) red[p][wid] = part;
    }
    __syncthreads();
    if (tid < PPB) {
        out[blockIdx.x * PPB + tid] =
            b2[0] + red[tid][0] + red[tid][1] + red[tid][2] + red[tid][3];
    }
}

extern "C" void kernel_launch(void* const* d_in, const int* in_sizes, int n_in,
                              void* d_out, int out_size, void* d_ws, size_t ws_size,
                              hipStream_t stream) {
    const float* x   = (const float*)d_in[0];
    const int*   ei  = (const int*)d_in[1];
    const int*   tar = (const int*)d_in[2];
    const float* W1  = (const float*)d_in[3];
    const float* b1  = (const float*)d_in[4];
    const float* W2  = (const float*)d_in[5];
    const float* b2  = (const float*)d_in[6];
    float* out = (float*)d_out;
    int* ws = (int*)d_ws;

    k_init<<<1, 1024, 0, stream>>>(tar, ws);
    k_mega<<<NBLK, NTHR, 0, stream>>>(x, ei, tar, W1, b1, W2, b2, out, ws);
}